// Round 1
// 375.293 us; speedup vs baseline: 1.0042x; 1.0042x over previous
//
#include <hip/hip_runtime.h>
#include <hip/hip_bf16.h>

constexpr int B  = 8;
constexpr int LQ = 2048;
constexpr int LK = 4096;
constexpr int C  = 1024;
constexpr int H  = 16;
constexpr int D  = 64;
constexpr int CS = 8;
constexpr int KC = 256;
constexpr float SCALE = 0.125f;

typedef __attribute__((ext_vector_type(8))) short short8;
typedef __attribute__((ext_vector_type(4))) float f32x4;

union FragU { unsigned u[4]; short8 s; float4 f; };

__device__ inline unsigned bfp(float a, float b) {
  float2 f2; f2.x = a; f2.y = b;
  __hip_bfloat162 h = __float22bfloat162_rn(f2); // v_cvt_pk_bf16_f32
  return *reinterpret_cast<unsigned*>(&h);
}

// ---------------------------------------------------------------------------
// Kernel 1: bucket index per kv token (fp32-exact dot; bf16 would flip signs
// of near-zero codes and change bucket assignment vs the reference).
// ---------------------------------------------------------------------------
__global__ __launch_bounds__(256) void k_codes(
    const float* __restrict__ kmat, const float* __restrict__ Wc,
    const float* __restrict__ bc, int* __restrict__ idx)
{
  __shared__ float wS[CS * C]; // 32 KB
  const int tid = threadIdx.x;
  {
    const float4* wsrc = (const float4*)Wc;
    float4* wdst = (float4*)wS;
#pragma unroll
    for (int i = 0; i < 8; ++i) wdst[tid + i * 256] = wsrc[tid + i * 256];
  }
  float bcr[CS];
#pragma unroll
  for (int j = 0; j < CS; ++j) bcr[j] = bc[j];
  __syncthreads();

  const int wave = tid >> 6, lane = tid & 63;

  for (int i = 0; i < 8; ++i) {
    const int r = blockIdx.x * 32 + wave * 8 + i;
    const float4* krow = (const float4*)(kmat + (size_t)r * C);
    float acc[CS];
#pragma unroll
    for (int j = 0; j < CS; ++j) acc[j] = 0.f;
#pragma unroll
    for (int rep = 0; rep < 4; ++rep) {
      float4 kv = krow[rep * 64 + lane];
      const int dbase = (rep * 64 + lane) * 4;
#pragma unroll
      for (int j = 0; j < CS; ++j) {
        float4 wv = *(const float4*)&wS[j * C + dbase];
        acc[j] += kv.x * wv.x + kv.y * wv.y + kv.z * wv.z + kv.w * wv.w;
      }
    }
#pragma unroll
    for (int j = 0; j < CS; ++j) {
#pragma unroll
      for (int off = 32; off >= 1; off >>= 1)
        acc[j] += __shfl_xor(acc[j], off, 64);
    }
    if (lane == 0) {
      int ix = 0;
#pragma unroll
      for (int j = 0; j < CS; ++j)
        ix |= ((acc[j] + bcr[j]) >= 0.f ? 1 : 0) << (7 - j);
      idx[r] = ix;
    }
  }
}

// ---------------------------------------------------------------------------
// Kernel 2 (fused): per-batch histogram + scan + permutation + counts tile.
// One block per batch. Widened to 1024 threads: the histogram and permute
// phases (the serial bulk -- only 8 blocks on 256 CUs) now take 4 rounds
// instead of 16. Scan phase guarded to the first 256 threads (4 full waves).
// ---------------------------------------------------------------------------
__global__ __launch_bounds__(1024) void k_sort(
    const int* __restrict__ idx, int* __restrict__ offs,
    int* __restrict__ cnti, int* __restrict__ perm,
    float4* __restrict__ vfc)
{
  __shared__ int idxS[LK];  // 16 KB
  __shared__ int hist[KC];
  __shared__ int cur[KC];
  __shared__ int wsum[4];
  const int b = blockIdx.x, t = threadIdx.x;
  const int lane = t & 63, w = t >> 6;

  if (t < KC) hist[t] = 0;
  __syncthreads();
  for (int i = t; i < LK; i += 1024) {
    const int ix = idx[b * LK + i];
    idxS[i] = ix;
    atomicAdd(&hist[ix], 1);
  }
  __syncthreads();

  int myc = 0, scan = 0;
  if (t < KC) {
    myc = hist[t];
    scan = myc;
#pragma unroll
    for (int off = 1; off < 64; off <<= 1) {
      int u = __shfl_up(scan, off, 64);
      if (lane >= off) scan += u;
    }
    if (lane == 63) wsum[w] = scan;
  }
  __syncthreads();
  if (t < KC) {
    int base = 0;
#pragma unroll
    for (int i = 0; i < 4; ++i) base += (i < w) ? wsum[i] : 0;
    const int start = b * LK + base + scan - myc;
    offs[b * KC + t] = start;
    cnti[b * KC + t] = myc;
    cur[t] = start;
  }
  __syncthreads();

  // build permutation via LDS cursors
  for (int i = t; i < LK; i += 1024) {
    const int pos = atomicAdd(&cur[idxS[i]], 1);
    perm[pos] = b * LK + i;
  }

  // counts fragment tile (MFMA B-layout, col 0 of each 16-col group)
  if (t < 512) {
    const int qc = t >> 6, ln = t & 63;
    FragU u4;
    if ((ln & 15) == 0) {
      const int* cs = hist + (qc * 4 + (ln >> 4)) * 8;
      u4.u[0] = bfp((float)cs[0], (float)cs[1]);
      u4.u[1] = bfp((float)cs[2], (float)cs[3]);
      u4.u[2] = bfp((float)cs[4], (float)cs[5]);
      u4.u[3] = bfp((float)cs[6], (float)cs[7]);
    } else {
      u4.u[0] = u4.u[1] = u4.u[2] = u4.u[3] = 0u;
    }
    vfc[b * 512 + t] = u4.f;
  }
}

// ---------------------------------------------------------------------------
// Kernel 3: gather-sum bucket rows. Output is now a LINEAR bf16-pair image
// vtmp[b][bucket][col/2] (uint = 2 packed bf16): each thread stores 8 B
// contiguous, the block stores 2 KB contiguous -- fully coalesced, replacing
// the old 2 B x 16 B-stride scatter whose 64 B sectors were co-written by 8
// different blocks across XCDs (~128 MB sector traffic for a 4 MB image).
// ---------------------------------------------------------------------------
__global__ __launch_bounds__(256) void k_gather(
    const float* __restrict__ v, const int* __restrict__ perm,
    const int* __restrict__ offs, const int* __restrict__ cnti,
    unsigned* __restrict__ vtmp)
{
  __shared__ int permS[512];
  const int t = threadIdx.x;
  const int ix = blockIdx.x, b = blockIdx.y;
  const int start = offs[b * KC + ix];
  const int cnt = cnti[b * KC + ix];

  float4 acc = make_float4(0.f, 0.f, 0.f, 0.f);
  for (int base = 0; base < cnt; base += 512) {
    const int n = min(512, cnt - base);
    __syncthreads();
    for (int i = t; i < n; i += 256) permS[i] = perm[start + base + i];
    __syncthreads();
    int i = 0;
    for (; i + 4 <= n; i += 4) {
      const int r0 = permS[i], r1 = permS[i + 1];
      const int r2 = permS[i + 2], r3 = permS[i + 3];
      float4 a = *(const float4*)(v + (size_t)r0 * C + t * 4);
      float4 b4 = *(const float4*)(v + (size_t)r1 * C + t * 4);
      float4 c4 = *(const float4*)(v + (size_t)r2 * C + t * 4);
      float4 d4 = *(const float4*)(v + (size_t)r3 * C + t * 4);
      acc.x += a.x + b4.x + c4.x + d4.x;
      acc.y += a.y + b4.y + c4.y + d4.y;
      acc.z += a.z + b4.z + c4.z + d4.z;
      acc.w += a.w + b4.w + c4.w + d4.w;
    }
    for (; i < n; ++i) {
      const int r0 = permS[i];
      float4 a = *(const float4*)(v + (size_t)r0 * C + t * 4);
      acc.x += a.x; acc.y += a.y; acc.z += a.z; acc.w += a.w;
    }
  }

  // cols t*4 .. t*4+3 -> uints t*2, t*2+1 (lo short = even col)
  uint2 wv;
  wv.x = bfp(acc.x, acc.y);
  wv.y = bfp(acc.z, acc.w);
  *((uint2*)(vtmp + (((size_t)(b * KC + ix)) << 9)) + t) = wv;
}

// ---------------------------------------------------------------------------
// Kernel 3b: repack linear vtmp into the MFMA B-fragment image k_attn reads.
// Block (o, b) owns bucket group o*8..o*8+7, whose 8 buckets are exactly the
// 8 shorts of each output float4 slot. 4 MB in + 4 MB out total (~2 us).
//   slot(n,o) = ((o>>2)*4 + (n>>4))*64 + (o&3)*16 + (n&15), short j = bucket
//   o*8+j, col = h*64+n  (identical image to the previous direct scatter).
// ---------------------------------------------------------------------------
__global__ __launch_bounds__(256) void k_repack(
    const unsigned* __restrict__ vtmp, float4* __restrict__ vfb)
{
  __shared__ unsigned U[8][522]; // pitch 522: banks (j*10+p)%32 all distinct
  const int o = blockIdx.x, b = blockIdx.y, t = threadIdx.x;
  for (int i = t; i < 8 * 512; i += 256) {
    const int j = i >> 9, c = i & 511;
    U[j][c] = vtmp[(((size_t)(b * KC + o * 8 + j)) << 9) + c];
  }
  __syncthreads();
#pragma unroll
  for (int pp = 0; pp < 2; ++pp) {
    const int p = t + pp * 256;        // column pair: cols 2p, 2p+1
    const int h = p >> 5;              // (2p) >> 6
    const int n = (2 * p) & 63;        // even, so slots s and s+1 pair up
    const int s = ((o >> 2) * 4 + (n >> 4)) * 64 + (o & 3) * 16 + (n & 15);
    unsigned Ur[8];
#pragma unroll
    for (int j = 0; j < 8; ++j) Ur[j] = U[j][p];
    FragU lo, hi;
#pragma unroll
    for (int j = 0; j < 4; ++j) {
      lo.u[j] = (Ur[2 * j] & 0xffffu) | (Ur[2 * j + 1] << 16);
      hi.u[j] = (Ur[2 * j] >> 16) | (Ur[2 * j + 1] & 0xffff0000u);
    }
    float4* outp = vfb + (size_t)(b * 16 + h) * 2048 + s;
    outp[0] = lo.f;   // col 2p
    outp[1] = hi.f;   // col 2p+1
  }
}

// ---------------------------------------------------------------------------
// Kernel 4: attention. Adds (a) bijective XCD swizzle so each XCD owns one
// batch -> its vfb working set is 512 KB (L2-resident) instead of 4 MB, and
// (b) non-temporal out stores so the 64 MB streaming write doesn't evict vfb.
// ---------------------------------------------------------------------------
__global__ __launch_bounds__(256) void k_attn(
    const float* __restrict__ q, const float* __restrict__ cb,
    const float4* __restrict__ vfb, const float4* __restrict__ vfc,
    float* __restrict__ out)
{
  __shared__ __align__(16) char smem[18432];
  float4* QA  = (float4*)smem;             // 1024 f4 (16384 B)
  float4* CBf = (float4*)(smem + 16384);   // 128 f4  (2048 B)
  float*  TS  = (float*)smem;              // alias over QA after t-MFMA

  const int tid = threadIdx.x;
  const int lane = tid & 63, wq = tid >> 6, quad = lane >> 4;

  // XCD-aware swizzle: grid (16,16,8) = 2048 blocks, lin%8 = XCD (round
  // robin). Remap so XCD c gets ns in [c*256, c*256+256) = all (q0,h) tiles
  // of batch c. 2048 % 8 == 0 -> bijective.
  const int lin = blockIdx.x + 16 * blockIdx.y + 256 * blockIdx.z;
  const int ns = (lin & 7) * 256 + (lin >> 3);
  const int q0 = (ns & 15) * 128;
  const int h = (ns >> 4) & 15;
  const int b = ns >> 8;

#pragma unroll
  for (int it = 0; it < 4; ++it) {
    const int od = tid & 7, m = it * 32 + (tid >> 3);
    const float* src = q + (size_t)(b * LQ + q0 + m) * C + h * D + od * 8;
    float4 f0 = *(const float4*)src, f1 = *(const float4*)(src + 4);
    FragU u;
    u.u[0] = bfp(f0.x * SCALE, f0.y * SCALE);
    u.u[1] = bfp(f0.z * SCALE, f0.w * SCALE);
    u.u[2] = bfp(f1.x * SCALE, f1.y * SCALE);
    u.u[3] = bfp(f1.z * SCALE, f1.w * SCALE);
    QA[((m >> 4) * 2 + (od >> 2)) * 64 + (od & 3) * 16 + (m & 15)] = u.f;
  }
  if (tid < 128) {
    const int od = tid & 7, j = tid >> 3;
    const float* src = cb + (size_t)j * C + h * D + od * 8;
    float4 f0 = *(const float4*)src, f1 = *(const float4*)(src + 4);
    FragU u;
    u.u[0] = bfp(f0.x, f0.y); u.u[1] = bfp(f0.z, f0.w);
    u.u[2] = bfp(f1.x, f1.y); u.u[3] = bfp(f1.z, f1.w);
    CBf[(od >> 2) * 64 + (od & 3) * 16 + j] = u.f;
  }
  __syncthreads();

  f32x4 tacc[2];
#pragma unroll
  for (int mt2 = 0; mt2 < 2; ++mt2) {
    const int mt = wq * 2 + mt2;
    FragU a0, a1, b0, b1;
    a0.f = QA[(mt * 2 + 0) * 64 + lane];
    a1.f = QA[(mt * 2 + 1) * 64 + lane];
    b0.f = CBf[0 * 64 + lane];
    b1.f = CBf[1 * 64 + lane];
    f32x4 z = {0.f, 0.f, 0.f, 0.f};
    z = __builtin_amdgcn_mfma_f32_16x16x32_bf16(a0.s, b0.s, z, 0, 0, 0);
    z = __builtin_amdgcn_mfma_f32_16x16x32_bf16(a1.s, b1.s, z, 0, 0, 0);
    tacc[mt2] = z;
  }
  __syncthreads();

#pragma unroll
  for (int mt2 = 0; mt2 < 2; ++mt2) {
    const int mt = wq * 2 + mt2;
#pragma unroll
    for (int r = 0; r < 4; ++r)
      TS[mt * 272 + (quad * 4 + r) * 17 + (lane & 15)] = tacc[mt2][r];
  }
  float t0[16], t1[16];
#pragma unroll
  for (int j = 0; j < 16; ++j) {
    t0[j] = TS[(wq * 2 + 0) * 272 + (lane & 15) * 17 + j];
    t1[j] = TS[(wq * 2 + 1) * 272 + (lane & 15) * 17 + j];
  }

  float esl0[8], esl1[8];
#pragma unroll
  for (int c = 0; c < 8; ++c) {
    esl0[c] = __expf(((c & 4) ? t0[5] : t0[13]) + ((c & 2) ? t0[6] : t0[14]) +
                     ((c & 1) ? t0[7] : t0[15]));
    esl1[c] = __expf(((c & 4) ? t1[5] : t1[13]) + ((c & 2) ? t1[6] : t1[14]) +
                     ((c & 1) ? t1[7] : t1[15]));
  }

  f32x4 acc[2][5];
#pragma unroll
  for (int i = 0; i < 2; ++i)
#pragma unroll
    for (int t_ = 0; t_ < 5; ++t_) acc[i][t_] = (f32x4){0.f, 0.f, 0.f, 0.f};

  const float4* vb = vfb + (size_t)(b * 16 + h) * 2048 + lane;
  const float4* vc = vfc + b * 512 + lane;

#pragma unroll
  for (int qc = 0; qc < 8; ++qc) {
    FragU bf0, bf1_, bf2, bf3, cf;
    bf0.f = vb[(qc * 4 + 0) * 64];
    bf1_.f = vb[(qc * 4 + 1) * 64];
    bf2.f = vb[(qc * 4 + 2) * 64];
    bf3.f = vb[(qc * 4 + 3) * 64];
    cf.f  = vc[qc * 64];

    const int u = qc * 4 + quad;
    const float eshi0 = __expf(
        ((u & 16) ? t0[0] : t0[8]) + ((u & 8) ? t0[1] : t0[9]) +
        ((u & 4) ? t0[2] : t0[10]) + ((u & 2) ? t0[3] : t0[11]) +
        ((u & 1) ? t0[4] : t0[12]));
    const float eshi1 = __expf(
        ((u & 16) ? t1[0] : t1[8]) + ((u & 8) ? t1[1] : t1[9]) +
        ((u & 4) ? t1[2] : t1[10]) + ((u & 2) ? t1[3] : t1[11]) +
        ((u & 1) ? t1[4] : t1[12]));

    FragU a0, a1;
    a0.u[0] = bfp(eshi0 * esl0[0], eshi0 * esl0[1]);
    a0.u[1] = bfp(eshi0 * esl0[2], eshi0 * esl0[3]);
    a0.u[2] = bfp(eshi0 * esl0[4], eshi0 * esl0[5]);
    a0.u[3] = bfp(eshi0 * esl0[6], eshi0 * esl0[7]);
    a1.u[0] = bfp(eshi1 * esl1[0], eshi1 * esl1[1]);
    a1.u[1] = bfp(eshi1 * esl1[2], eshi1 * esl1[3]);
    a1.u[2] = bfp(eshi1 * esl1[4], eshi1 * esl1[5]);
    a1.u[3] = bfp(eshi1 * esl1[6], eshi1 * esl1[7]);

    acc[0][0] = __builtin_amdgcn_mfma_f32_16x16x32_bf16(a0.s, bf0.s,  acc[0][0], 0, 0, 0);
    acc[1][0] = __builtin_amdgcn_mfma_f32_16x16x32_bf16(a1.s, bf0.s,  acc[1][0], 0, 0, 0);
    acc[0][1] = __builtin_amdgcn_mfma_f32_16x16x32_bf16(a0.s, bf1_.s, acc[0][1], 0, 0, 0);
    acc[1][1] = __builtin_amdgcn_mfma_f32_16x16x32_bf16(a1.s, bf1_.s, acc[1][1], 0, 0, 0);
    acc[0][2] = __builtin_amdgcn_mfma_f32_16x16x32_bf16(a0.s, bf2.s,  acc[0][2], 0, 0, 0);
    acc[1][2] = __builtin_amdgcn_mfma_f32_16x16x32_bf16(a1.s, bf2.s,  acc[1][2], 0, 0, 0);
    acc[0][3] = __builtin_amdgcn_mfma_f32_16x16x32_bf16(a0.s, bf3.s,  acc[0][3], 0, 0, 0);
    acc[1][3] = __builtin_amdgcn_mfma_f32_16x16x32_bf16(a1.s, bf3.s,  acc[1][3], 0, 0, 0);
    acc[0][4] = __builtin_amdgcn_mfma_f32_16x16x32_bf16(a0.s, cf.s,   acc[0][4], 0, 0, 0);
    acc[1][4] = __builtin_amdgcn_mfma_f32_16x16x32_bf16(a1.s, cf.s,   acc[1][4], 0, 0, 0);
  }

  const int srcl = lane & 48;
#pragma unroll
  for (int mt2 = 0; mt2 < 2; ++mt2) {
#pragma unroll
    for (int r = 0; r < 4; ++r) {
      const float den = __shfl(acc[mt2][4][r], srcl, 64);
      const float inv = 1.0f / den;
      const int row = q0 + wq * 32 + mt2 * 16 + quad * 4 + r;
      float* op = out + (size_t)(b * LQ + row) * C + h * D + (lane & 15);
#pragma unroll
      for (int t_ = 0; t_ < 4; ++t_)
        __builtin_nontemporal_store(acc[mt2][t_][r] * inv, op + t_ * 16);
    }
  }
}

// ---------------------------------------------------------------------------
extern "C" void kernel_launch(void* const* d_in, const int* in_sizes, int n_in,
                              void* d_out, int out_size, void* d_ws, size_t ws_size,
                              hipStream_t stream) {
  (void)in_sizes; (void)n_in; (void)out_size; (void)ws_size;
  const float* q  = (const float*)d_in[0];
  const float* k  = (const float*)d_in[1];
  const float* v  = (const float*)d_in[2];
  const float* Wc = (const float*)d_in[3];
  const float* bc = (const float*)d_in[4];
  const float* cb = (const float*)d_in[5];
  float* out = (float*)d_out;

  char* ws = (char*)d_ws;
  int*    idxp  = (int*)ws;                        // 128 KB
  int*    offsp = (int*)(ws + 0x20000);            // 8 KB
  int*    cntip = (int*)(ws + 0x22000);            // 8 KB
  int*    permp = (int*)(ws + 0x24000);            // 128 KB
  float4* vfcp  = (float4*)(ws + 0x44000);         // 64 KB
  unsigned short* vbfp = (unsigned short*)(ws + 0x60000);  // 4 MB fragment image
  unsigned* vtmpp = (unsigned*)(ws + 0x460000);            // 4 MB linear image

  hipLaunchKernelGGL(k_codes, dim3(1024), dim3(256), 0, stream,
                     k, Wc, bc, idxp);
  hipLaunchKernelGGL(k_sort, dim3(B), dim3(1024), 0, stream,
                     idxp, offsp, cntip, permp, vfcp);
  hipLaunchKernelGGL(k_gather, dim3(KC, B), dim3(256), 0, stream,
                     v, permp, offsp, cntip, vtmpp);
  hipLaunchKernelGGL(k_repack, dim3(32, B), dim3(256), 0, stream,
                     vtmpp, (float4*)vbfp);
  hipLaunchKernelGGL(k_attn, dim3(LQ / 128, H, B), dim3(256), 0, stream,
                     q, cb, (const float4*)vbfp, (const float4*)vfcp, out);
}